// Round 1
// 669.378 us; speedup vs baseline: 1.1194x; 1.1194x over previous
//
#include <hip/hip_runtime.h>
#include <stdint.h>

// InnerMonologue: PR = hid @ W_to + b_to ; proj = PR @ W_from + b_from
// out = mask ? proj : hid ; mask = parity of cumulative thought-token count (row 0).
// Outputs concat: PR (B,S,P) | out (B,S,H) | is_private (B,S) | usage (B), all fp32.
//
// R1: split the 1-block/CU mega-fused kernel (135KB LDS, 20.8% occupancy, all
// pipes idle) into two occupancy-friendly GEMMs. GEMM2 re-reads PR from out0
// (fp32) and converts in staging -> no extra workspace, same numerics.

#define H 2048
#define P 256
#define BB 4
#define S 8192
#define M_TOTAL (BB * S)

typedef __bf16 bf16x8 __attribute__((ext_vector_type(8)));
typedef float f32x4 __attribute__((ext_vector_type(4)));

__device__ __forceinline__ ushort f2b(float f) {
  // fp32 -> bf16 round-to-nearest-even
  uint32_t u = __float_as_uint(f);
  u += 0x7fffu + ((u >> 16) & 1u);
  return (ushort)(u >> 16);
}

// ---------------- mask / is_private / usage ----------------
// 256 threads, 32 tokens each. Parity prefix via ballot scan (no serial LDS chain).
__global__ void mask_kernel(const int* __restrict__ tok, const int* __restrict__ tt_p,
                            float* __restrict__ maskf, float* __restrict__ out2,
                            float* __restrict__ out3) {
  __shared__ unsigned long long wpar[4];
  __shared__ int wcnt[4];
  const int t = threadIdx.x;
  const int lane = t & 63, w = t >> 6;
  const int tt = tt_p[0];
  const int base = t * 32;
  unsigned bits = 0;
  for (int i = 0; i < 32; i++) bits |= (unsigned)(tok[base + i] == tt) << i;
  const int par = __popc(bits) & 1;
  const unsigned long long bal = __ballot(par != 0);
  if (lane == 0) wpar[w] = bal;
  __syncthreads();
  int pre = 0;
  for (int j = 0; j < w; j++) pre ^= (int)(__popcll(wpar[j]) & 1);
  pre ^= (int)(__popcll(bal & ((1ull << lane) - 1ull)) & 1);
  int cnt = 0;
  for (int i = 0; i < 32; i++) {
    int inc = __popc(bits << (31 - i)) & 1;  // inclusive parity of bits[0..i]
    int bit = pre ^ inc;
    cnt += bit;
    float fb = (float)bit;
    maskf[base + i] = fb;
    out2[0 * S + base + i] = fb;
    out2[1 * S + base + i] = fb;
    out2[2 * S + base + i] = fb;
    out2[3 * S + base + i] = fb;
  }
  for (int off = 32; off; off >>= 1) cnt += __shfl_down(cnt, off);
  if (lane == 0) wcnt[w] = cnt;
  __syncthreads();
  if (t < BB) {
    int tot = wcnt[0] + wcnt[1] + wcnt[2] + wcnt[3];
    out3[t] = (float)tot / (float)S;
  }
}

// ---------------- weight transpose + fp32->bf16 ----------------
// in: R x C fp32 row-major ; out: C x R bf16 row-major
__global__ void transpose_cvt(const float* __restrict__ in, ushort* __restrict__ out,
                              int R, int C) {
  __shared__ float tile[32][33];
  const int c0 = blockIdx.x * 32, r0 = blockIdx.y * 32;
  const int tx = threadIdx.x, ty = threadIdx.y;  // 32 x 8
#pragma unroll
  for (int j = 0; j < 32; j += 8)
    tile[ty + j][tx] = in[(size_t)(r0 + ty + j) * C + c0 + tx];
  __syncthreads();
#pragma unroll
  for (int j = 0; j < 32; j += 8)
    out[(size_t)(c0 + ty + j) * R + r0 + tx] = f2b(tile[tx][ty + j]);
}

// ---------------- GEMM1: PR(64x256 per block) = hid @ W_to + b_to ----------------
// grid 512 x 512 threads. LDS = 64x72 + 256x72 ushort = 46KB -> 2 blocks/CU resident.
// 8 waves each own 64 rows x 32 cols (acc[4][2]).
__global__ __launch_bounds__(512) void gemm1(
    const float* __restrict__ hid,
    const ushort* __restrict__ wtT,   // P x H bf16  (W_to^T)
    const float* __restrict__ b_to,
    float* __restrict__ out0)         // (B*S, P) fp32
{
  __shared__ ushort sA[64 * 72];
  __shared__ ushort sW[256 * 72];
  const int tid = threadIdx.x;
  const int lane = tid & 63, wid = tid >> 6;
  const int quad = lane >> 4, l16 = lane & 15;
  const int row0 = blockIdx.x * 64;

  f32x4 acc[4][2];
  const f32x4 zero = {0.f, 0.f, 0.f, 0.f};
#pragma unroll
  for (int i = 0; i < 4; i++)
#pragma unroll
    for (int j = 0; j < 2; j++) acc[i][j] = zero;

  for (int k0 = 0; k0 < H; k0 += 64) {
    // stage A: 64 rows x 64 k, fp32 -> bf16 (1024 float4 units / 512 thr)
#pragma unroll
    for (int p = 0; p < 2; p++) {
      int u = p * 512 + tid;
      int r = u >> 4, cc = u & 15;
      const float4 v = *(const float4*)(hid + (size_t)(row0 + r) * H + k0 + cc * 4);
      ushort4 b;
      b.x = f2b(v.x); b.y = f2b(v.y); b.z = f2b(v.z); b.w = f2b(v.w);
      *(ushort4*)(sA + r * 72 + cc * 4) = b;
    }
    // stage W_to^T: 256 n-rows x 64 k (bf16 copy, 2048 int4 units / 512 thr)
#pragma unroll
    for (int p = 0; p < 4; p++) {
      int u = p * 512 + tid;
      int n = u >> 3, s = u & 7;
      *(int4*)(sW + n * 72 + s * 8) = *(const int4*)(wtT + (size_t)n * H + k0 + s * 8);
    }
    __syncthreads();
#pragma unroll
    for (int kk = 0; kk < 64; kk += 32) {
      bf16x8 af[4], bfr[2];
#pragma unroll
      for (int t = 0; t < 4; t++)
        af[t] = *(const bf16x8*)(sA + (t * 16 + l16) * 72 + kk + quad * 8);
#pragma unroll
      for (int t = 0; t < 2; t++)
        bfr[t] = *(const bf16x8*)(sW + (wid * 32 + t * 16 + l16) * 72 + kk + quad * 8);
#pragma unroll
      for (int i = 0; i < 4; i++)
#pragma unroll
        for (int j = 0; j < 2; j++)
          acc[i][j] = __builtin_amdgcn_mfma_f32_16x16x32_bf16(af[i], bfr[j], acc[i][j], 0, 0, 0);
    }
    __syncthreads();
  }

  // epilogue: +b_to, write PR fp32
#pragma unroll
  for (int i = 0; i < 4; i++) {
#pragma unroll
    for (int j = 0; j < 2; j++) {
      int col = wid * 32 + j * 16 + l16;
      float bias = b_to[col];
#pragma unroll
      for (int e = 0; e < 4; e++) {
        int row = i * 16 + quad * 4 + e;
        out0[(size_t)(row0 + row) * P + col] = acc[i][j][e] + bias;
      }
    }
  }
}

// ---------------- GEMM2: out(128x128 per block) = blend(PR @ W_from + b_from) ----------------
// grid 4096 x 512 threads. LDS = 128x72 + 128x72 ushort = 36.9KB -> 2+ blocks/CU.
// 8 waves as 4x2: each 32 rows x 64 cols (acc[2][4]). A re-read from out0 fp32 -> bf16.
// XCD swizzle: each XCD gets 32 consecutive m-tiles; nblk fast -> PR panel stays in L2.
__global__ __launch_bounds__(512) void gemm2(
    const float* __restrict__ pr,     // out0: (B*S, P) fp32
    const ushort* __restrict__ wfT,   // H x P bf16  (W_from^T)
    const float* __restrict__ b_from,
    const float* __restrict__ maskf,
    const float* __restrict__ hid,
    float* __restrict__ out1)         // (B*S, H) fp32
{
  __shared__ ushort sA[128 * 72];
  __shared__ ushort sW[128 * 72];
  const int tid = threadIdx.x;
  const int lane = tid & 63, wid = tid >> 6;
  const int quad = lane >> 4, l16 = lane & 15;

  // bijective XCD swizzle (4096 % 8 == 0): XCD x gets u0 in [x*512, x*512+512)
  const int u0 = (blockIdx.x & 7) * 512 + (blockIdx.x >> 3);
  const int mblk = u0 >> 4, nblk = u0 & 15;
  const int row0 = mblk * 128, nc0 = nblk * 128;

  const int wr = wid >> 1;  // 0..3 : 32 rows
  const int wc = wid & 1;   // 0..1 : 64 cols

  f32x4 acc[2][4];
  const f32x4 zero = {0.f, 0.f, 0.f, 0.f};
#pragma unroll
  for (int i = 0; i < 2; i++)
#pragma unroll
    for (int j = 0; j < 4; j++) acc[i][j] = zero;

  for (int k0 = 0; k0 < P; k0 += 64) {
    // stage A: 128 rows x 64 k from PR fp32 -> bf16 (2048 float4 / 512 thr)
#pragma unroll
    for (int p = 0; p < 4; p++) {
      int u = p * 512 + tid;
      int r = u >> 4, cc = u & 15;
      const float4 v = *(const float4*)(pr + (size_t)(row0 + r) * P + k0 + cc * 4);
      ushort4 b;
      b.x = f2b(v.x); b.y = f2b(v.y); b.z = f2b(v.z); b.w = f2b(v.w);
      *(ushort4*)(sA + r * 72 + cc * 4) = b;
    }
    // stage W_from^T chunk: 128 n-rows x 64 k (1024 int4 / 512 thr)
#pragma unroll
    for (int p = 0; p < 2; p++) {
      int u = p * 512 + tid;
      int n = u >> 3, s = u & 7;
      *(int4*)(sW + n * 72 + s * 8) = *(const int4*)(wfT + (size_t)(nc0 + n) * P + k0 + s * 8);
    }
    __syncthreads();
#pragma unroll
    for (int kk = 0; kk < 64; kk += 32) {
      bf16x8 af[2], bfr[4];
#pragma unroll
      for (int t = 0; t < 2; t++)
        af[t] = *(const bf16x8*)(sA + (wr * 32 + t * 16 + l16) * 72 + kk + quad * 8);
#pragma unroll
      for (int t = 0; t < 4; t++)
        bfr[t] = *(const bf16x8*)(sW + (wc * 64 + t * 16 + l16) * 72 + kk + quad * 8);
#pragma unroll
      for (int i = 0; i < 2; i++)
#pragma unroll
        for (int j = 0; j < 4; j++)
          acc[i][j] = __builtin_amdgcn_mfma_f32_16x16x32_bf16(af[i], bfr[j], acc[i][j], 0, 0, 0);
    }
    __syncthreads();
  }

  // epilogue: +b_from, blend with hid (row-granular mask), store
#pragma unroll
  for (int i = 0; i < 2; i++) {
#pragma unroll
    for (int e = 0; e < 4; e++) {
      int row = wr * 32 + i * 16 + quad * 4 + e;
      size_t gr = (size_t)(row0 + row);
      float m = maskf[gr & (S - 1)];
      if (m != 0.0f) {
#pragma unroll
        for (int j = 0; j < 4; j++) {
          int col = nc0 + wc * 64 + j * 16 + l16;
          out1[gr * H + col] = acc[i][j][e] + b_from[col];
        }
      } else {
#pragma unroll
        for (int j = 0; j < 4; j++) {
          int col = nc0 + wc * 64 + j * 16 + l16;
          out1[gr * H + col] = hid[gr * H + col];
        }
      }
    }
  }
}

extern "C" void kernel_launch(void* const* d_in, const int* in_sizes, int n_in,
                              void* d_out, int out_size, void* d_ws, size_t ws_size,
                              hipStream_t stream) {
  const float* hid    = (const float*)d_in[0];
  const float* W_to   = (const float*)d_in[1];
  const float* b_to   = (const float*)d_in[2];
  const float* W_from = (const float*)d_in[3];
  const float* b_from = (const float*)d_in[4];
  const int*   tok    = (const int*)d_in[5];
  const int*   tt     = (const int*)d_in[6];

  // workspace: W_to^T bf16 (P*H) | W_from^T bf16 (H*P) | mask float (S)  ~2.1MB
  ushort* wtT = (ushort*)d_ws;
  ushort* wfT = wtT + (size_t)P * H;
  float* maskf = (float*)(wfT + (size_t)H * P);

  float* out0 = (float*)d_out;                    // private_reasoning (B,S,P)
  float* out1 = out0 + (size_t)BB * S * P;        // output (B,S,H)
  float* out2 = out1 + (size_t)BB * S * H;        // is_private (B,S)
  float* out3 = out2 + (size_t)BB * S;            // subspace_usage (B)

  hipLaunchKernelGGL(mask_kernel, dim3(1), dim3(256), 0, stream, tok, tt, maskf, out2, out3);
  hipLaunchKernelGGL(transpose_cvt, dim3(P / 32, H / 32), dim3(32, 8), 0, stream, W_to, wtT, H, P);
  hipLaunchKernelGGL(transpose_cvt, dim3(H / 32, P / 32), dim3(32, 8), 0, stream, W_from, wfT, P, H);
  hipLaunchKernelGGL(gemm1, dim3(M_TOTAL / 64), dim3(512), 0, stream, hid, wtT, b_to, out0);
  hipLaunchKernelGGL(gemm2, dim3((M_TOTAL / 128) * (H / 128)), dim3(512), 0, stream,
                     out0, wfT, b_from, maskf, hid, out1);
}